// Round 10
// baseline (409.218 us; speedup 1.0000x reference)
//
#include <hip/hip_runtime.h>

// InfluenceEncoder FUSED: B=4096, N=257, D=16, H=128.
// One kernel, 512 blocks x 512 threads (8 waves); block = 8 batches.
// Phase 0: stage Wfc as f16 into LDS (once per block; kills the 134 MB of
//   redundant per-wave Wfc loads the split version paid).
// Phase 1: wave wv owns batch blockIdx*8+wv ENTIRELY (256 agents):
//   8 m-tiles x 4 col-tiles of mfma_f32_32x32x16_f16, depth-2 A pipeline.
//   Weights computed from A-regs (x,y at k=0,1; f6 at k=6) by lo lanes ->
//   wave-private LDS slice (barrier-free). relu-bias fold via nb = -bfc.
//   Epilogue: xor32 combine, wsum butterfly, ragg = relu(pacc*inv + bfc)
//   -> f16 LDS [8][136] (pad 8 halfs: 2-way max bank conflict on reads).
// Phase 2 (one barrier): 8 waves x 8 col-tiles: out = ragg @ Wagg^T + bagg,
//   4x mfma_f32_16x16x32_f16 (K=128). A rows 8..15 garbage, not stored.
// No workspace round-trip, no second launch.
// REGISTER RULE (R5/R7): only min=max waves_per_eu pins an honest budget.
// (4,4) -> 128 VGPR target; liveness ~100; 2 blocks/CU.

typedef _Float16 half_t;
typedef half_t f16x4v __attribute__((ext_vector_type(4)));
typedef half_t f16x8 __attribute__((ext_vector_type(8)));
typedef float f32x4 __attribute__((ext_vector_type(4)));
typedef float f32x16 __attribute__((ext_vector_type(16)));

__global__ __launch_bounds__(512)
__attribute__((amdgpu_waves_per_eu(4, 4)))
void fused_kernel(
    const float* __restrict__ x,     // [4096,257,16]
    const float* __restrict__ Wfc,   // [128,16]
    const float* __restrict__ bfc,   // [128]
    const float* __restrict__ Wagg,  // [128,128]
    const float* __restrict__ bagg,  // [128]
    float* __restrict__ out)         // [4096,128]
{
    const int t    = threadIdx.x;
    const int lane = t & 63;
    const int wv   = t >> 6;      // 0..7
    const int lm   = lane & 31;
    const int hi   = lane >> 5;

    __shared__ half_t wfc_lds[128 * 16];   // f16 Wfc row-major, 4 KB
    __shared__ half_t ragg[8][136];        // relu(agg) f16, +8 pad
    __shared__ float  wls[8][32];          // per-wave weight slice

    // ---- phase 0: stage Wfc f16 (512 threads x 4 elems) ----
    {
        const float4 v = *(const float4*)(Wfc + t * 4);
        *(f16x4v*)(wfc_lds + t * 4) =
            (f16x4v){(half_t)v.x, (half_t)v.y, (half_t)v.z, (half_t)v.w};
    }
    __syncthreads();

    const int b = blockIdx.x * 8 + wv;
    const float* xb = x + (size_t)b * (257 * 16);
    const float2 ego = *(const float2*)xb;

    // ---- B-frags from LDS + folded -bias ----
    f16x8 bfr[4];
    float nb[4];
    #pragma unroll
    for (int ct = 0; ct < 4; ++ct) {
        bfr[ct] = *(const f16x8*)(wfc_lds + (size_t)(ct * 32 + lm) * 16 + hi * 8);
        nb[ct] = -bfc[ct * 32 + lm];
    }

    const f32x16 zc = {};   // single zero C block, hoisted (no per-MFMA re-zero)

    // ---- phase 1: full batch per wave, 8 m-tiles, depth-2 pipeline ----
    float4 s0[2], s1[2];
    #pragma unroll
    for (int i = 0; i < 2; ++i) {
        const float* rp = xb + (size_t)(1 + i * 32 + lm) * 16 + hi * 8;
        s0[i] = *(const float4*)rp;
        s1[i] = *(const float4*)(rp + 4);
    }

    float wsum = 0.f;
    float pacc[4] = {0.f, 0.f, 0.f, 0.f};

    #pragma unroll
    for (int tm = 0; tm < 8; ++tm) {
        const int cur = tm & 1;
        const float4 a0 = s0[cur], a1 = s1[cur];
        if (tm < 6) {
            const float* rp = xb + (size_t)(1 + (tm + 2) * 32 + lm) * 16 + hi * 8;
            s0[cur] = *(const float4*)rp;
            s1[cur] = *(const float4*)(rp + 4);
        }
        if (hi == 0) {   // weights from in-flight regs (k=0,1 pos; k=6 flag)
            const float dx = a0.x - ego.x, dy = a0.y - ego.y;
            float w = 1.0f / (sqrtf(dx * dx + dy * dy) + 1.0f);
            if (a1.z == 1.0f) w *= 5.0f;
            wls[wv][lm] = w;
            wsum += w;
        }
        const f16x8 afr = (f16x8){(half_t)a0.x, (half_t)a0.y, (half_t)a0.z, (half_t)a0.w,
                                  (half_t)a1.x, (half_t)a1.y, (half_t)a1.z, (half_t)a1.w};
        float4 w4[4];
        #pragma unroll
        for (int g = 0; g < 4; ++g)
            w4[g] = *(const float4*)(&wls[wv][g * 8 + hi * 4]);
        #pragma unroll
        for (int ct = 0; ct < 4; ++ct) {
            const f32x16 d = __builtin_amdgcn_mfma_f32_32x32x16_f16(afr, bfr[ct], zc, 0, 0, 0);
            // D: col=lane&31, row=(r&3)+8*(r>>2)+4*hi
            #pragma unroll
            for (int r = 0; r < 16; ++r)
                pacc[ct] = fmaf(w4[r >> 2][r & 3], fmaxf(d[r], nb[ct]), pacc[ct]);
        }
    }

    // ---- phase-1 epilogue: combine halves, normalize, relu, to LDS ----
    #pragma unroll
    for (int ct = 0; ct < 4; ++ct) pacc[ct] += __shfl_xor(pacc[ct], 32);
    #pragma unroll
    for (int off = 32; off > 0; off >>= 1) wsum += __shfl_xor(wsum, off);
    const float inv = 1.0f / (wsum + 1e-10f);
    if (hi == 0) {
        #pragma unroll
        for (int ct = 0; ct < 4; ++ct) {
            const float e = fmaxf(fmaf(pacc[ct], inv, -nb[ct]), 0.f);
            ragg[wv][ct * 32 + lm] = (half_t)e;
        }
    }
    __syncthreads();

    // ---- phase 2: out(8x128) = ragg @ Wagg^T + bagg; wave = 16-col tile ----
    const int lr = lane & 15;
    const int lq = lane >> 4;
    const int col = wv * 16 + lr;
    const float bb = bagg[col];
    f32x4 acc = (f32x4){bb, bb, bb, bb};
    const float* wrow = Wagg + (size_t)col * 128;

    #pragma unroll
    for (int kk = 0; kk < 4; ++kk) {
        const int k0 = kk * 32 + lq * 8;
        const f16x8 a = *(const f16x8*)(&ragg[lr & 7][k0]);  // rows 8-15 garbage
        const float4 wg0 = *(const float4*)(wrow + k0);
        const float4 wg1 = *(const float4*)(wrow + k0 + 4);
        const f16x8 bf = (f16x8){(half_t)wg0.x, (half_t)wg0.y, (half_t)wg0.z, (half_t)wg0.w,
                                 (half_t)wg1.x, (half_t)wg1.y, (half_t)wg1.z, (half_t)wg1.w};
        acc = __builtin_amdgcn_mfma_f32_16x16x32_f16(a, bf, acc, 0, 0, 0);
    }

    // D: col=lane&15, row=lq*4+jj; only rows 0..7 are real batches
    if (lq < 2) {
        #pragma unroll
        for (int jj = 0; jj < 4; ++jj)
            out[(size_t)(blockIdx.x * 8 + lq * 4 + jj) * 128 + col] = acc[jj];
    }
}

extern "C" void kernel_launch(void* const* d_in, const int* in_sizes, int n_in,
                              void* d_out, int out_size, void* d_ws, size_t ws_size,
                              hipStream_t stream) {
    const float* x    = (const float*)d_in[0];
    const float* Wfc  = (const float*)d_in[1];
    const float* bfc  = (const float*)d_in[2];
    const float* Wagg = (const float*)d_in[3];
    const float* bagg = (const float*)d_in[4];
    float* out = (float*)d_out;

    fused_kernel<<<dim3(512), dim3(512), 0, stream>>>(x, Wfc, bfc, Wagg, bagg, out);
}